// Round 19
// baseline (410.686 us; speedup 1.0000x reference)
//
#include <hip/hip_runtime.h>
#include <hip/hip_fp16.h>
#include <math.h>

#define NEG 0.2f
#define CBITS 7               // coarse bucket = dst >> 7 (128 nodes/bucket)
#define CNODES 128
#define PADK 88               // 176B row stride: 16B-aligned, 2-way-bank-alias only

typedef _Float16 half8 __attribute__((ext_vector_type(8)));
typedef float f32x4 __attribute__((ext_vector_type(4)));

__device__ __forceinline__ float eluf(float x) { return x > 0.0f ? x : __expf(x) - 1.0f; }
__device__ __forceinline__ float h2f(ushort u) { return __half2float(__ushort_as_half(u)); }
__device__ __forceinline__ ushort f2h(float f) { return __half_as_ushort(__float2half_rn(f)); }
template <int PAT>
__device__ __forceinline__ float swzf(float v) {
  return __int_as_float(__builtin_amdgcn_ds_swizzle(__float_as_int(v), PAT));
}

// ---------------- K-1: W -> fp16 W^T (wt[col][k]), once ----------------
__global__ __launch_bounds__(256) void k_wt(const float* __restrict__ W,
                                            ushort* __restrict__ wt_h) {
  __shared__ float t[64 * 68];
  const int tid = threadIdx.x;
  const int kb = blockIdx.x * 64;
#pragma unroll
  for (int p = 0; p < 4; ++p) {
    int q = tid + p * 256;
    int r = q >> 4, c4 = q & 15;
    float4 v = *(const float4*)&W[(size_t)(kb + r) * 64 + c4 * 4];
    *(float4*)&t[r * 68 + c4 * 4] = v;
  }
  __syncthreads();
#pragma unroll
  for (int p = 0; p < 2; ++p) {
    int i = tid + p * 256;
    int col = i >> 3, g = i & 7;
    ushort4 a, b;
    a.x = f2h(t[(g * 8 + 0) * 68 + col]); a.y = f2h(t[(g * 8 + 1) * 68 + col]);
    a.z = f2h(t[(g * 8 + 2) * 68 + col]); a.w = f2h(t[(g * 8 + 3) * 68 + col]);
    b.x = f2h(t[(g * 8 + 4) * 68 + col]); b.y = f2h(t[(g * 8 + 5) * 68 + col]);
    b.z = f2h(t[(g * 8 + 6) * 68 + col]); b.w = f2h(t[(g * 8 + 7) * 68 + col]);
    *(ushort4*)&wt_h[(size_t)col * 512 + kb + g * 8] = a;
    *(ushort4*)&wt_h[(size_t)col * 512 + kb + g * 8 + 4] = b;
  }
}

// ---------------- K0: coarse histogram ----------------
__global__ __launch_bounds__(256) void k_hist(const int* __restrict__ ei,
                                              int* __restrict__ coarse_hist,
                                              int E, int NBK) {
  __shared__ int lh[1024];
  const int tid = threadIdx.x;
  for (int q = tid; q < NBK; q += 256) lh[q] = 0;
  __syncthreads();
  int e_base = (int)blockIdx.x * 16384;
#pragma unroll 4
  for (int u = 0; u < 16; ++u) {
    int e = e_base + u * 1024 + tid * 4;
    if (e + 3 < E) {
      int4 d4 = *(const int4*)&ei[E + e];
      atomicAdd(&lh[d4.x >> CBITS], 1);
      atomicAdd(&lh[d4.y >> CBITS], 1);
      atomicAdd(&lh[d4.z >> CBITS], 1);
      atomicAdd(&lh[d4.w >> CBITS], 1);
    } else {
      for (int v = 0; v < 4; ++v) {
        int ee = e + v;
        if (ee < E) atomicAdd(&lh[ei[E + ee] >> CBITS], 1);
      }
    }
  }
  __syncthreads();
  for (int q = tid; q < NBK; q += 256) {
    int c = lh[q];
    if (c > 0) atomicAdd(&coarse_hist[q], c);
  }
}

// ---------------- K2: scan coarse histogram + write sentinels ----------------
__global__ __launch_bounds__(1024) void k_coarse_scan(const int* __restrict__ coarse_hist,
                                                      int* __restrict__ coarse_off,
                                                      int* __restrict__ cursor,
                                                      float* __restrict__ asrc1,
                                                      float* __restrict__ asrc2,
                                                      int NBK, int E, int N) {
  __shared__ int s[1024];
  int t = threadIdx.x;
  int own = t < NBK ? coarse_hist[t] : 0;
  s[t] = own;
  __syncthreads();
  for (int o = 1; o < 1024; o <<= 1) {
    int add = t >= o ? s[t - o] : 0;
    __syncthreads();
    s[t] += add;
    __syncthreads();
  }
  if (t < NBK) {
    int excl = s[t] - own;
    coarse_off[t] = excl;
    cursor[t] = excl;
  }
  if (t == 0) coarse_off[NBK] = E;
  if (t < 8) asrc1[(size_t)N * 8 + t] = -1e30f;
  if (t == 8) asrc2[N] = -1e30f;
}

// ---------------- K1: MFMA fp16 gemm1 blocks [0,NBg) ∥ two-pass scatter [NBg,NBg+NB3) ----
__global__ __launch_bounds__(256) void k_gemm_scatter(const float* __restrict__ x,
                                                      const ushort* __restrict__ wt_h,
                                                      ushort* __restrict__ h1g,
                                                      const float* __restrict__ as1,
                                                      const float* __restrict__ ad1,
                                                      float* __restrict__ asrc1,
                                                      float* __restrict__ adst1,
                                                      const int* __restrict__ ei,
                                                      int* __restrict__ cursor,
                                                      int* __restrict__ bucketed,
                                                      int N, int E, int NBg, int NBK) {
  __shared__ ushort xs_h[64 * PADK];   // 11264 B
  __shared__ ushort ws_h[64 * PADK];   // 11264 B
  const int tid = threadIdx.x;

  if ((int)blockIdx.x >= NBg) {
    // -------- two-pass bucket scatter: 16384 edges/block --------
    int* hist = (int*)xs_h;
    int* basev = ((int*)xs_h) + 1024;
    int* hist2 = (int*)ws_h;
    for (int q = tid; q < NBK; q += 256) { hist[q] = 0; hist2[q] = 0; }
    __syncthreads();
    const int e_base = ((int)blockIdx.x - NBg) * 16384;
#pragma unroll 4
    for (int u = 0; u < 16; ++u) {
      int e = e_base + u * 1024 + tid * 4;
      if (e + 3 < E) {
        int4 d4 = *(const int4*)&ei[E + e];
        atomicAdd(&hist[d4.x >> CBITS], 1);
        atomicAdd(&hist[d4.y >> CBITS], 1);
        atomicAdd(&hist[d4.z >> CBITS], 1);
        atomicAdd(&hist[d4.w >> CBITS], 1);
      } else {
        for (int v = 0; v < 4; ++v) {
          int ee = e + v;
          if (ee < E) atomicAdd(&hist[ei[E + ee] >> CBITS], 1);
        }
      }
    }
    __syncthreads();
    for (int q = tid; q < NBK; q += 256) {
      int c = hist[q];
      basev[q] = c > 0 ? atomicAdd(&cursor[q], c) : 0;
    }
    __syncthreads();
#pragma unroll 2
    for (int u = 0; u < 16; ++u) {
      int e = e_base + u * 1024 + tid * 4;
      if (e + 3 < E) {
        int4 s4 = *(const int4*)&ei[e];
        int4 d4 = *(const int4*)&ei[E + e];
        int b, r;
        b = d4.x >> CBITS; r = atomicAdd(&hist2[b], 1);
        bucketed[basev[b] + r] = (s4.x << CBITS) | (d4.x & (CNODES - 1));
        b = d4.y >> CBITS; r = atomicAdd(&hist2[b], 1);
        bucketed[basev[b] + r] = (s4.y << CBITS) | (d4.y & (CNODES - 1));
        b = d4.z >> CBITS; r = atomicAdd(&hist2[b], 1);
        bucketed[basev[b] + r] = (s4.z << CBITS) | (d4.z & (CNODES - 1));
        b = d4.w >> CBITS; r = atomicAdd(&hist2[b], 1);
        bucketed[basev[b] + r] = (s4.w << CBITS) | (d4.w & (CNODES - 1));
      } else {
        for (int v = 0; v < 4; ++v) {
          int ee = e + v;
          if (ee < E) {
            int d = ei[E + ee];
            int b = d >> CBITS;
            int r = atomicAdd(&hist2[b], 1);
            bucketed[basev[b] + r] = (ei[ee] << CBITS) | (d & (CNODES - 1));
          }
        }
      }
    }
    return;
  }

  // -------- gemm branch: 64x64 tile, BK=64, mfma_f32_16x16x32_f16 --------
  const int n0 = blockIdx.x * 64;
  const int lane = tid & 63;
  const int m0 = (tid >> 6) * 16;

  f32x4 acc[4];
#pragma unroll
  for (int t = 0; t < 4; ++t) acc[t] = (f32x4){0.f, 0.f, 0.f, 0.f};

  for (int kc = 0; kc < 512; kc += 64) {
#pragma unroll
    for (int p = 0; p < 4; ++p) {
      int q = tid + p * 256;
      int r = q >> 4, c4 = q & 15;
      int n = n0 + r;
      if (n >= N) n = N - 1;
      float4 v = *(const float4*)&x[(size_t)n * 512 + kc + c4 * 4];
      ushort4 u;
      u.x = f2h(v.x); u.y = f2h(v.y); u.z = f2h(v.z); u.w = f2h(v.w);
      *(ushort4*)&xs_h[r * PADK + c4 * 4] = u;
    }
#pragma unroll
    for (int p = 0; p < 2; ++p) {
      int i = tid + p * 256;
      int col = i >> 3, g = i & 7;
      uint4 v = *(const uint4*)&wt_h[(size_t)col * 512 + kc + g * 8];
      *(uint4*)&ws_h[col * PADK + g * 8] = v;
    }
    __syncthreads();

#pragma unroll
    for (int kk = 0; kk < 64; kk += 32) {
      half8 a = *(const half8*)&xs_h[(m0 + (lane & 15)) * PADK + kk + (lane >> 4) * 8];
#pragma unroll
      for (int t = 0; t < 4; ++t) {
        half8 b = *(const half8*)&ws_h[(t * 16 + (lane & 15)) * PADK + kk + (lane >> 4) * 8];
        acc[t] = __builtin_amdgcn_mfma_f32_16x16x32_f16(a, b, acc[t], 0, 0, 0);
      }
    }
    __syncthreads();
  }

  // epilogue: acc -> LDS fp16 (C layout: col=lane&15, row=(lane>>4)*4+reg)
#pragma unroll
  for (int t = 0; t < 4; ++t)
#pragma unroll
    for (int r = 0; r < 4; ++r) {
      int row = m0 + (lane >> 4) * 4 + r;
      int col = t * 16 + (lane & 15);
      xs_h[row * PADK + col] = f2h(acc[t][r]);
    }
  __syncthreads();

#pragma unroll
  for (int p = 0; p < 4; ++p) {
    int q = tid + p * 256;
    int r = q >> 4, g = q & 15;
    int n = n0 + r;
    if (n < N) *(ushort4*)&h1g[(size_t)n * 64 + g * 4] = *(ushort4*)&xs_h[r * PADK + g * 4];
  }
#pragma unroll
  for (int u2 = 0; u2 < 2; ++u2) {
    int idx = tid + u2 * 256;
    int r = idx >> 3, h = idx & 7;
    int n = n0 + r;
    if (n < N) {
      float s = 0.f, dd = 0.f;
#pragma unroll
      for (int c = 0; c < 8; ++c) {
        float hv = h2f(xs_h[r * PADK + h * 8 + c]);
        s += hv * as1[h * 8 + c];
        dd += hv * ad1[h * 8 + c];
      }
      asrc1[(size_t)n * 8 + h] = s;
      adst1[(size_t)n * 8 + h] = dd;
    }
  }
}

// ---------------- K4: per-bucket fine CSR, rows padded to 8, pad-slot-only sentinel ----
__global__ __launch_bounds__(256) void k_fine_csr(const int* __restrict__ bucketed,
                                                  const int* __restrict__ coarse_off,
                                                  int* __restrict__ rowstart,
                                                  int* __restrict__ deg,
                                                  int* __restrict__ csr, int N) {
  __shared__ int h[CNODES];
  __shared__ int excl[CNODES];
  const int tid = threadIdx.x;
  const int bkt = blockIdx.x;
  const int base = coarse_off[bkt];
  const int cnt = coarse_off[bkt + 1] - base;
  const int base_p = base + 8 * CNODES * bkt;

  if (tid < CNODES) h[tid] = 0;
  __syncthreads();
  for (int i = tid; i < cnt; i += 256) atomicAdd(&h[bucketed[base + i] & (CNODES - 1)], 1);
  __syncthreads();
  if (tid < 64) {
    int a = h[2 * tid], c = h[2 * tid + 1];
    int pa = (a + 7) & ~7, pc = (c + 7) & ~7;
    int ps = pa + pc;
    int sv = ps;
    for (int o = 1; o < 64; o <<= 1) {
      int tv = __shfl_up(sv, o, 64);
      if (tid >= o) sv += tv;
    }
    int e0v = sv - ps;
    excl[2 * tid] = e0v;
    excl[2 * tid + 1] = e0v + pa;
  }
  __syncthreads();
  if (tid < CNODES) {
    int node = bkt * CNODES + tid;
    int dv = h[tid];
    int e0v = excl[tid];
    if (node < N) {
      rowstart[node] = base_p + e0v;
      deg[node] = dv;
    }
    // pad-slot-only sentinel fill (<=7 per node)
    int pe = (dv + 7) & ~7;
    for (int k = dv; k < pe; ++k) csr[base_p + e0v + k] = N;
  }
  __syncthreads();
  if (tid < CNODES) h[tid] = 0;
  __syncthreads();
  for (int i = tid; i < cnt; i += 256) {
    int v = bucketed[base + i];
    int loc = v & (CNODES - 1);
    int r = atomicAdd(&h[loc], 1);
    csr[base_p + excl[loc] + r] = v >> CBITS;
  }
}

// ---------------- layer-1 aggregation (swizzle-broadcast) FUSED with layer-2 dense ------
__global__ __launch_bounds__(256) void agg1_l2(const int* __restrict__ rowstart,
                                               const int* __restrict__ deg,
                                               const int* __restrict__ csr,
                                               const float* __restrict__ asrc,
                                               const float* __restrict__ adst,
                                               const ushort* __restrict__ h1g,
                                               const float* __restrict__ b1,
                                               const float* __restrict__ W2,
                                               const float* __restrict__ as2,
                                               const float* __restrict__ ad2,
                                               ushort* __restrict__ h2g,
                                               float* __restrict__ asrc2,
                                               float* __restrict__ adst2, int N) {
  __shared__ float w2s[64 * 40];
  __shared__ float acts[4][68];
  const int tid = threadIdx.x;
  const int wave = tid >> 6;
  const int lane = tid & 63;

  for (int q = tid; q < 640; q += 256)
    *(float4*)&w2s[q * 4] = *(const float4*)&W2[q * 4];

  const int gw = (blockIdx.x * 256 + tid) >> 6;
  const bool valid = gw < N;
  const int d = valid ? gw : N - 1;

  const int el = lane & 1;
  const int H = lane >> 3;               // head (producer AND consumer role)
  const int c2 = (lane >> 1) & 3;
  const int cp = H * 4 + c2;             // channel pair 0..31
  const int cl = lane & 7;               // producer edge index

  const float adp = adst[d * 8 + H];
  const int rs = rowstart[d];
  const int n = deg[d];
  const int np = (n + 7) & ~7;
  float accx = 0.0f, accy = 0.0f, zsv = 0.0f;
  for (int i = 0; i < np; i += 8) {
    const int4 A = *(const int4*)&csr[rs + i];
    const int4 B = *(const int4*)&csr[rs + i + 4];
    const int sl = csr[rs + i + cl];
    const float al = asrc[sl * 8 + H] + adp;
    const float pl = __expf(fmaxf(al, NEG * al));
    const float p0 = swzf<0x019>(pl);
    const float p1 = swzf<0x059>(pl);
    const float p2 = swzf<0x099>(pl);
    const float p3 = swzf<0x0D9>(pl);
    const int s0 = el ? A.y : A.x;
    const int s1 = el ? A.w : A.z;
    const int s2 = el ? B.y : B.x;
    const int s3 = el ? B.w : B.z;
    const uint u0 = *(const uint*)&h1g[s0 * 64 + 2 * cp];
    const uint u1 = *(const uint*)&h1g[s1 * 64 + 2 * cp];
    const uint u2 = *(const uint*)&h1g[s2 * 64 + 2 * cp];
    const uint u3 = *(const uint*)&h1g[s3 * 64 + 2 * cp];
    accx = fmaf(p0, h2f((ushort)(u0 & 0xffff)), accx);
    accy = fmaf(p0, h2f((ushort)(u0 >> 16)), accy);
    accx = fmaf(p1, h2f((ushort)(u1 & 0xffff)), accx);
    accy = fmaf(p1, h2f((ushort)(u1 >> 16)), accy);
    accx = fmaf(p2, h2f((ushort)(u2 & 0xffff)), accx);
    accy = fmaf(p2, h2f((ushort)(u2 >> 16)), accy);
    accx = fmaf(p3, h2f((ushort)(u3 & 0xffff)), accx);
    accy = fmaf(p3, h2f((ushort)(u3 >> 16)), accy);
    zsv += (p0 + p1) + (p2 + p3);
  }
  accx += __shfl_xor(accx, 1, 64);
  accy += __shfl_xor(accy, 1, 64);
  zsv += __shfl_xor(zsv, 1, 64);
  {
    const float a = asrc[d * 8 + H] + adp;
    const float p = __expf(fmaxf(a, NEG * a));
    const uint u = *(const uint*)&h1g[d * 64 + 2 * cp];
    accx = fmaf(p, h2f((ushort)(u & 0xffff)), accx);
    accy = fmaf(p, h2f((ushort)(u >> 16)), accy);
    zsv += p;
  }
  const float inv = 1.0f / (zsv + 1e-16f);
  if (!el) {
    acts[wave][2 * cp] = eluf(accx * inv + b1[2 * cp]);
    acts[wave][2 * cp + 1] = eluf(accy * inv + b1[2 * cp + 1]);
  }
  __syncthreads();

  float val = 0.0f;
  if (lane < 40) {
#pragma unroll
    for (int c = 0; c < 64; c += 4) {
      float4 a = *(const float4*)&acts[wave][c];
      val += a.x * w2s[(c + 0) * 40 + lane] + a.y * w2s[(c + 1) * 40 + lane] +
             a.z * w2s[(c + 2) * 40 + lane] + a.w * w2s[(c + 3) * 40 + lane];
    }
  }
  if (valid && lane < 40) h2g[(size_t)gw * 40 + lane] = f2h(val);

  float v1 = lane < 40 ? val * as2[lane] : 0.0f;
  float v2 = lane < 40 ? val * ad2[lane] : 0.0f;
#pragma unroll
  for (int o = 1; o < 64; o <<= 1) {
    v1 += __shfl_xor(v1, o, 64);
    v2 += __shfl_xor(v2, o, 64);
  }
  if (valid && lane == 0) {
    asrc2[gw] = v1;
    adst2[gw] = v2;
  }
}

// ---------------- layer 2 aggregation: 40-active-lane gathers (80B/edge fetch) ----------
__global__ __launch_bounds__(256) void agg2(const int* __restrict__ rowstart,
                                            const int* __restrict__ deg,
                                            const int* __restrict__ csr,
                                            const float* __restrict__ asrc,
                                            const float* __restrict__ adst,
                                            const ushort* __restrict__ h2g,
                                            const float* __restrict__ b2,
                                            float* __restrict__ out, int N) {
  int wid = (blockIdx.x * 256 + threadIdx.x) >> 6;
  if (wid >= N) return;
  const int lane = threadIdx.x & 63;
  const int el = lane & 1;
  const int cp = lane >> 1;          // 0..31; gathers active only for cp<20
  const bool act_ln = cp < 20;
  const int cl = lane & 7;
  const int d = wid;
  const float ad = adst[d];
  const int rs = rowstart[d];
  const int n = deg[d];
  const int np = (n + 7) & ~7;
  float accx = 0.0f, accy = 0.0f, zsv = 0.0f;
  for (int i = 0; i < np; i += 8) {
    const int4 A = *(const int4*)&csr[rs + i];
    const int4 B = *(const int4*)&csr[rs + i + 4];
    const int sl = csr[rs + i + cl];
    const float al = asrc[sl] + ad;
    const float pl = __expf(fmaxf(al, NEG * al));
    const float p0 = swzf<0x001>(pl);
    const float p1 = swzf<0x041>(pl);
    const float p2 = swzf<0x081>(pl);
    const float p3 = swzf<0x0C1>(pl);
    if (act_ln) {
      const int s0 = el ? A.y : A.x;
      const int s1 = el ? A.w : A.z;
      const int s2 = el ? B.y : B.x;
      const int s3 = el ? B.w : B.z;
      const uint u0 = *(const uint*)&h2g[s0 * 40 + 2 * cp];
      const uint u1 = *(const uint*)&h2g[s1 * 40 + 2 * cp];
      const uint u2 = *(const uint*)&h2g[s2 * 40 + 2 * cp];
      const uint u3 = *(const uint*)&h2g[s3 * 40 + 2 * cp];
      accx = fmaf(p0, h2f((ushort)(u0 & 0xffff)), accx);
      accy = fmaf(p0, h2f((ushort)(u0 >> 16)), accy);
      accx = fmaf(p1, h2f((ushort)(u1 & 0xffff)), accx);
      accy = fmaf(p1, h2f((ushort)(u1 >> 16)), accy);
      accx = fmaf(p2, h2f((ushort)(u2 & 0xffff)), accx);
      accy = fmaf(p2, h2f((ushort)(u2 >> 16)), accy);
      accx = fmaf(p3, h2f((ushort)(u3 & 0xffff)), accx);
      accy = fmaf(p3, h2f((ushort)(u3 >> 16)), accy);
    }
    zsv += (p0 + p1) + (p2 + p3);
  }
  accx += __shfl_xor(accx, 1, 64);
  accy += __shfl_xor(accy, 1, 64);
  zsv += __shfl_xor(zsv, 1, 64);
  {
    const float a = asrc[d] + ad;
    const float p = __expf(fmaxf(a, NEG * a));
    if (act_ln) {
      const uint u = *(const uint*)&h2g[d * 40 + 2 * cp];
      accx = fmaf(p, h2f((ushort)(u & 0xffff)), accx);
      accy = fmaf(p, h2f((ushort)(u >> 16)), accy);
    }
    zsv += p;
  }
  if (!el && act_ln) {
    const float inv = 1.0f / (zsv + 1e-16f);
    out[(size_t)d * 40 + 2 * cp] = accx * inv + b2[2 * cp];
    out[(size_t)d * 40 + 2 * cp + 1] = accy * inv + b2[2 * cp + 1];
  }
}

extern "C" void kernel_launch(void* const* d_in, const int* in_sizes, int n_in,
                              void* d_out, int out_size, void* d_ws, size_t ws_size,
                              hipStream_t stream) {
  const float* x   = (const float*)d_in[0];
  const int*   ei  = (const int*)d_in[1];
  const float* W1  = (const float*)d_in[2];
  const float* as1 = (const float*)d_in[3];
  const float* ad1 = (const float*)d_in[4];
  const float* b1  = (const float*)d_in[5];
  const float* W2  = (const float*)d_in[6];
  const float* as2 = (const float*)d_in[7];
  const float* ad2 = (const float*)d_in[8];
  const float* b2  = (const float*)d_in[9];
  float* out = (float*)d_out;

  const int N = in_sizes[0] / 512;
  const int E = in_sizes[1] / 2;
  const int NBK = (N + CNODES - 1) / CNODES;

  float* ws = (float*)d_ws;
  size_t o = 0;
  float* asrc1 = ws + o; o += (size_t)N * 8 + 8;
  float* adst1 = ws + o; o += (size_t)N * 8;
  float* asrc2 = ws + o; o += (size_t)N + 1;
  float* adst2 = ws + o; o += (size_t)N;
  ushort* h1g  = (ushort*)(ws + o); o += (size_t)N * 32 + 64;
  ushort* h2g  = (ushort*)(ws + o); o += (size_t)N * 20 + 64;
  ushort* wt_h = (ushort*)(ws + o); o += 64 * 512 / 2 + 16;
  int* deg         = (int*)(ws + o); o += (size_t)N;
  int* rowstart    = (int*)(ws + o); o += (size_t)N;
  int* coarse_hist = (int*)(ws + o); o += 1024;
  int* coarse_off  = (int*)(ws + o); o += 1056;
  int* cursor      = (int*)(ws + o); o += 1024;
  int* bucketed    = (int*)(ws + o); o += (size_t)E;
  int* csr         = (int*)(ws + o); o += (size_t)E + 8 * CNODES * (size_t)NBK + 64;

  hipMemsetAsync(coarse_hist, 0, 1024 * sizeof(int), stream);
  hipMemsetAsync(h1g + (size_t)N * 64, 0, 128 * sizeof(ushort), stream);
  hipMemsetAsync(h2g + (size_t)N * 40, 0, 64 * sizeof(ushort), stream);

  const int NBg = (N + 63) / 64;
  const int NBc = (E + 16383) / 16384;
  const int NB3 = (E + 16383) / 16384;

  k_wt<<<8, 256, 0, stream>>>(W1, wt_h);
  k_hist<<<NBc, 256, 0, stream>>>(ei, coarse_hist, E, NBK);
  k_coarse_scan<<<1, 1024, 0, stream>>>(coarse_hist, coarse_off, cursor, asrc1, asrc2,
                                        NBK, E, N);

  k_gemm_scatter<<<NBg + NB3, 256, 0, stream>>>(x, wt_h, h1g, as1, ad1, asrc1, adst1, ei,
                                                cursor, bucketed, N, E, NBg, NBK);

  k_fine_csr<<<NBK, 256, 0, stream>>>(bucketed, coarse_off, rowstart, deg, csr, N);

  agg1_l2<<<(N * 64 + 255) / 256, 256, 0, stream>>>(rowstart, deg, csr, asrc1, adst1, h1g,
                                                    b1, W2, as2, ad2, h2g, asrc2, adst2, N);

  agg2<<<(N * 64 + 255) / 256, 256, 0, stream>>>(rowstart, deg, csr, asrc2, adst2, h2g, b2,
                                                 out, N);
}

// Round 20
// 374.215 us; speedup vs baseline: 1.0975x; 1.0975x over previous
//
#include <hip/hip_runtime.h>
#include <hip/hip_fp16.h>
#include <math.h>

#define NEG 0.2f
#define CBITS 7               // coarse bucket = dst >> 7 (128 nodes/bucket)
#define CNODES 128
#define PADK 88               // 176B row stride: 16B-aligned, 2-way-bank-alias only

typedef _Float16 half8 __attribute__((ext_vector_type(8)));
typedef float f32x4 __attribute__((ext_vector_type(4)));

__device__ __forceinline__ float eluf(float x) { return x > 0.0f ? x : __expf(x) - 1.0f; }
__device__ __forceinline__ float h2f(ushort u) { return __half2float(__ushort_as_half(u)); }
__device__ __forceinline__ ushort f2h(float f) { return __half_as_ushort(__float2half_rn(f)); }

// ---------------- K-1: W -> fp16 W^T (wt[col][k]), once ----------------
__global__ __launch_bounds__(256) void k_wt(const float* __restrict__ W,
                                            ushort* __restrict__ wt_h) {
  __shared__ float t[64 * 68];
  const int tid = threadIdx.x;
  const int kb = blockIdx.x * 64;
#pragma unroll
  for (int p = 0; p < 4; ++p) {
    int q = tid + p * 256;
    int r = q >> 4, c4 = q & 15;
    float4 v = *(const float4*)&W[(size_t)(kb + r) * 64 + c4 * 4];
    *(float4*)&t[r * 68 + c4 * 4] = v;
  }
  __syncthreads();
#pragma unroll
  for (int p = 0; p < 2; ++p) {
    int i = tid + p * 256;
    int col = i >> 3, g = i & 7;
    ushort4 a, b;
    a.x = f2h(t[(g * 8 + 0) * 68 + col]); a.y = f2h(t[(g * 8 + 1) * 68 + col]);
    a.z = f2h(t[(g * 8 + 2) * 68 + col]); a.w = f2h(t[(g * 8 + 3) * 68 + col]);
    b.x = f2h(t[(g * 8 + 4) * 68 + col]); b.y = f2h(t[(g * 8 + 5) * 68 + col]);
    b.z = f2h(t[(g * 8 + 6) * 68 + col]); b.w = f2h(t[(g * 8 + 7) * 68 + col]);
    *(ushort4*)&wt_h[(size_t)col * 512 + kb + g * 8] = a;
    *(ushort4*)&wt_h[(size_t)col * 512 + kb + g * 8 + 4] = b;
  }
}

// ---------------- K0: coarse histogram ----------------
__global__ __launch_bounds__(256) void k_hist(const int* __restrict__ ei,
                                              int* __restrict__ coarse_hist,
                                              int E, int NBK) {
  __shared__ int lh[1024];
  const int tid = threadIdx.x;
  for (int q = tid; q < NBK; q += 256) lh[q] = 0;
  __syncthreads();
  int e_base = (int)blockIdx.x * 16384;
#pragma unroll 4
  for (int u = 0; u < 16; ++u) {
    int e = e_base + u * 1024 + tid * 4;
    if (e + 3 < E) {
      int4 d4 = *(const int4*)&ei[E + e];
      atomicAdd(&lh[d4.x >> CBITS], 1);
      atomicAdd(&lh[d4.y >> CBITS], 1);
      atomicAdd(&lh[d4.z >> CBITS], 1);
      atomicAdd(&lh[d4.w >> CBITS], 1);
    } else {
      for (int v = 0; v < 4; ++v) {
        int ee = e + v;
        if (ee < E) atomicAdd(&lh[ei[E + ee] >> CBITS], 1);
      }
    }
  }
  __syncthreads();
  for (int q = tid; q < NBK; q += 256) {
    int c = lh[q];
    if (c > 0) atomicAdd(&coarse_hist[q], c);
  }
}

// ---------------- K2: scan coarse histogram + write sentinels ----------------
__global__ __launch_bounds__(1024) void k_coarse_scan(const int* __restrict__ coarse_hist,
                                                      int* __restrict__ coarse_off,
                                                      int* __restrict__ cursor,
                                                      float* __restrict__ asrc1,
                                                      float* __restrict__ asrc2,
                                                      int NBK, int E, int N) {
  __shared__ int s[1024];
  int t = threadIdx.x;
  int own = t < NBK ? coarse_hist[t] : 0;
  s[t] = own;
  __syncthreads();
  for (int o = 1; o < 1024; o <<= 1) {
    int add = t >= o ? s[t - o] : 0;
    __syncthreads();
    s[t] += add;
    __syncthreads();
  }
  if (t < NBK) {
    int excl = s[t] - own;
    coarse_off[t] = excl;
    cursor[t] = excl;
  }
  if (t == 0) coarse_off[NBK] = E;
  if (t < 8) asrc1[(size_t)N * 8 + t] = -1e30f;
  if (t == 8) asrc2[N] = -1e30f;
}

// ---------------- K1: MFMA fp16 gemm1 blocks [0,NBg) ∥ two-pass scatter [NBg,NBg+NB3) ----
__global__ __launch_bounds__(256) void k_gemm_scatter(const float* __restrict__ x,
                                                      const ushort* __restrict__ wt_h,
                                                      ushort* __restrict__ h1g,
                                                      const float* __restrict__ as1,
                                                      const float* __restrict__ ad1,
                                                      float* __restrict__ asrc1,
                                                      float* __restrict__ adst1,
                                                      const int* __restrict__ ei,
                                                      int* __restrict__ cursor,
                                                      int* __restrict__ bucketed,
                                                      int N, int E, int NBg, int NBK) {
  __shared__ ushort xs_h[64 * PADK];   // 11264 B
  __shared__ ushort ws_h[64 * PADK];   // 11264 B
  const int tid = threadIdx.x;

  if ((int)blockIdx.x >= NBg) {
    // -------- two-pass bucket scatter: 16384 edges/block --------
    int* hist = (int*)xs_h;            // [0..1023]
    int* basev = ((int*)xs_h) + 1024;  // [1024..2047]  (8KB <= 11264B)
    int* hist2 = (int*)ws_h;           // [0..1023]
    for (int q = tid; q < NBK; q += 256) { hist[q] = 0; hist2[q] = 0; }
    __syncthreads();
    const int e_base = ((int)blockIdx.x - NBg) * 16384;
    // pass A: count
#pragma unroll 4
    for (int u = 0; u < 16; ++u) {
      int e = e_base + u * 1024 + tid * 4;
      if (e + 3 < E) {
        int4 d4 = *(const int4*)&ei[E + e];
        atomicAdd(&hist[d4.x >> CBITS], 1);
        atomicAdd(&hist[d4.y >> CBITS], 1);
        atomicAdd(&hist[d4.z >> CBITS], 1);
        atomicAdd(&hist[d4.w >> CBITS], 1);
      } else {
        for (int v = 0; v < 4; ++v) {
          int ee = e + v;
          if (ee < E) atomicAdd(&hist[ei[E + ee] >> CBITS], 1);
        }
      }
    }
    __syncthreads();
    for (int q = tid; q < NBK; q += 256) {
      int c = hist[q];
      basev[q] = c > 0 ? atomicAdd(&cursor[q], c) : 0;
    }
    __syncthreads();
    // pass B: rank + write (packed runs per bucket)
#pragma unroll 2
    for (int u = 0; u < 16; ++u) {
      int e = e_base + u * 1024 + tid * 4;
      if (e + 3 < E) {
        int4 s4 = *(const int4*)&ei[e];
        int4 d4 = *(const int4*)&ei[E + e];
        int b, r;
        b = d4.x >> CBITS; r = atomicAdd(&hist2[b], 1);
        bucketed[basev[b] + r] = (s4.x << CBITS) | (d4.x & (CNODES - 1));
        b = d4.y >> CBITS; r = atomicAdd(&hist2[b], 1);
        bucketed[basev[b] + r] = (s4.y << CBITS) | (d4.y & (CNODES - 1));
        b = d4.z >> CBITS; r = atomicAdd(&hist2[b], 1);
        bucketed[basev[b] + r] = (s4.z << CBITS) | (d4.z & (CNODES - 1));
        b = d4.w >> CBITS; r = atomicAdd(&hist2[b], 1);
        bucketed[basev[b] + r] = (s4.w << CBITS) | (d4.w & (CNODES - 1));
      } else {
        for (int v = 0; v < 4; ++v) {
          int ee = e + v;
          if (ee < E) {
            int d = ei[E + ee];
            int b = d >> CBITS;
            int r = atomicAdd(&hist2[b], 1);
            bucketed[basev[b] + r] = (ei[ee] << CBITS) | (d & (CNODES - 1));
          }
        }
      }
    }
    return;
  }

  // -------- gemm branch: 64x64 tile, BK=64, mfma_f32_16x16x32_f16 --------
  const int n0 = blockIdx.x * 64;
  const int lane = tid & 63;
  const int m0 = (tid >> 6) * 16;

  f32x4 acc[4];
#pragma unroll
  for (int t = 0; t < 4; ++t) acc[t] = (f32x4){0.f, 0.f, 0.f, 0.f};

  for (int kc = 0; kc < 512; kc += 64) {
    // x tile 64r x 64k fp32->fp16
#pragma unroll
    for (int p = 0; p < 4; ++p) {
      int q = tid + p * 256;
      int r = q >> 4, c4 = q & 15;
      int n = n0 + r;
      if (n >= N) n = N - 1;
      float4 v = *(const float4*)&x[(size_t)n * 512 + kc + c4 * 4];
      ushort4 u;
      u.x = f2h(v.x); u.y = f2h(v.y); u.z = f2h(v.z); u.w = f2h(v.w);
      *(ushort4*)&xs_h[r * PADK + c4 * 4] = u;
    }
    // W^T tile: pure fp16 vector copy from pre-transposed wt_h
#pragma unroll
    for (int p = 0; p < 2; ++p) {
      int i = tid + p * 256;
      int col = i >> 3, g = i & 7;
      uint4 v = *(const uint4*)&wt_h[(size_t)col * 512 + kc + g * 8];
      *(uint4*)&ws_h[col * PADK + g * 8] = v;
    }
    __syncthreads();

#pragma unroll
    for (int kk = 0; kk < 64; kk += 32) {
      half8 a = *(const half8*)&xs_h[(m0 + (lane & 15)) * PADK + kk + (lane >> 4) * 8];
#pragma unroll
      for (int t = 0; t < 4; ++t) {
        half8 b = *(const half8*)&ws_h[(t * 16 + (lane & 15)) * PADK + kk + (lane >> 4) * 8];
        acc[t] = __builtin_amdgcn_mfma_f32_16x16x32_f16(a, b, acc[t], 0, 0, 0);
      }
    }
    __syncthreads();
  }

  // epilogue: acc -> LDS fp16 (C layout: col=lane&15, row=(lane>>4)*4+reg)
#pragma unroll
  for (int t = 0; t < 4; ++t)
#pragma unroll
    for (int r = 0; r < 4; ++r) {
      int row = m0 + (lane >> 4) * 4 + r;
      int col = t * 16 + (lane & 15);
      xs_h[row * PADK + col] = f2h(acc[t][r]);
    }
  __syncthreads();

#pragma unroll
  for (int p = 0; p < 4; ++p) {
    int q = tid + p * 256;
    int r = q >> 4, g = q & 15;
    int n = n0 + r;
    if (n < N) *(ushort4*)&h1g[(size_t)n * 64 + g * 4] = *(ushort4*)&xs_h[r * PADK + g * 4];
  }
#pragma unroll
  for (int u2 = 0; u2 < 2; ++u2) {
    int idx = tid + u2 * 256;
    int r = idx >> 3, h = idx & 7;
    int n = n0 + r;
    if (n < N) {
      float s = 0.f, dd = 0.f;
#pragma unroll
      for (int c = 0; c < 8; ++c) {
        float hv = h2f(xs_h[r * PADK + h * 8 + c]);
        s += hv * as1[h * 8 + c];
        dd += hv * ad1[h * 8 + c];
      }
      asrc1[(size_t)n * 8 + h] = s;
      adst1[(size_t)n * 8 + h] = dd;
    }
  }
}

// ---------------- K4: per-bucket fine CSR, rows padded to 8, pads = sentinel N ----------
__global__ __launch_bounds__(256) void k_fine_csr(const int* __restrict__ bucketed,
                                                  const int* __restrict__ coarse_off,
                                                  int* __restrict__ rowstart,
                                                  int* __restrict__ deg,
                                                  int* __restrict__ csr, int N) {
  __shared__ int h[CNODES];
  __shared__ int excl[CNODES];
  __shared__ int stot;
  const int tid = threadIdx.x;
  const int bkt = blockIdx.x;
  const int base = coarse_off[bkt];
  const int cnt = coarse_off[bkt + 1] - base;
  const int base_p = base + 8 * CNODES * bkt;

  if (tid < CNODES) h[tid] = 0;
  __syncthreads();
  for (int i = tid; i < cnt; i += 256) atomicAdd(&h[bucketed[base + i] & (CNODES - 1)], 1);
  __syncthreads();
  if (tid < 64) {
    int a = h[2 * tid], c = h[2 * tid + 1];
    int pa = (a + 7) & ~7, pc = (c + 7) & ~7;
    int ps = pa + pc;
    int sv = ps;
    for (int o = 1; o < 64; o <<= 1) {
      int tv = __shfl_up(sv, o, 64);
      if (tid >= o) sv += tv;
    }
    int e0v = sv - ps;
    excl[2 * tid] = e0v;
    excl[2 * tid + 1] = e0v + pa;
    if (tid == 63) stot = sv;
  }
  __syncthreads();
  if (tid < CNODES) {
    int node = bkt * CNODES + tid;
    if (node < N) {
      rowstart[node] = base_p + excl[tid];
      deg[node] = h[tid];
    }
  }
  const int tot = stot;
  __syncthreads();
  for (int i = tid; i < tot; i += 256) csr[base_p + i] = N;
  if (tid < CNODES) h[tid] = 0;
  __syncthreads();
  for (int i = tid; i < cnt; i += 256) {
    int v = bucketed[base + i];
    int loc = v & (CNODES - 1);
    int r = atomicAdd(&h[loc], 1);
    csr[base_p + excl[loc] + r] = v >> CBITS;
  }
}

// ---------------- layer-1 aggregation (paired-channel) FUSED with layer-2 dense ----------
__global__ __launch_bounds__(256) void agg1_l2(const int* __restrict__ rowstart,
                                               const int* __restrict__ deg,
                                               const int* __restrict__ csr,
                                               const float* __restrict__ asrc,
                                               const float* __restrict__ adst,
                                               const ushort* __restrict__ h1g,
                                               const float* __restrict__ b1,
                                               const float* __restrict__ W2,
                                               const float* __restrict__ as2,
                                               const float* __restrict__ ad2,
                                               ushort* __restrict__ h2g,
                                               float* __restrict__ asrc2,
                                               float* __restrict__ adst2, int N) {
  __shared__ float w2s[64 * 40];
  __shared__ float acts[4][68];
  const int tid = threadIdx.x;
  const int wave = tid >> 6;
  const int lane = tid & 63;

  for (int q = tid; q < 640; q += 256)
    *(float4*)&w2s[q * 4] = *(const float4*)&W2[q * 4];

  const int gw = (blockIdx.x * 256 + tid) >> 6;
  const bool valid = gw < N;
  const int d = valid ? gw : N - 1;

  const int cp = lane & 31;
  const int el = lane >> 5;
  const int H = cp >> 2;
  const int ph = lane >> 3;
  const int cl = lane & 7;
  const int pshift = H * 8 + el;

  const float ad_p = adst[d * 8 + ph];
  const float ad_H = adst[d * 8 + H];
  const int rs = rowstart[d];
  const int n = deg[d];
  const int np = (n + 7) & ~7;
  float accx = 0.0f, accy = 0.0f, zsv = 0.0f;
  for (int i = 0; i < np; i += 8) {
    const int4 A = *(const int4*)&csr[rs + i];
    const int4 B = *(const int4*)&csr[rs + i + 4];
    const int sl = csr[rs + i + cl];
    const float al = asrc[sl * 8 + ph] + ad_p;
    const float pl = __expf(fmaxf(al, NEG * al));
    int se[4], so[4];
    se[0] = A.x; so[0] = A.y; se[1] = A.z; so[1] = A.w;
    se[2] = B.x; so[2] = B.y; se[3] = B.z; so[3] = B.w;
#pragma unroll
    for (int j = 0; j < 4; ++j) {
      const int s = el ? so[j] : se[j];
      const float p = __shfl(pl, pshift + 2 * j, 64);
      const uint u = *(const uint*)&h1g[s * 64 + 2 * cp];
      accx = fmaf(p, h2f((ushort)(u & 0xffff)), accx);
      accy = fmaf(p, h2f((ushort)(u >> 16)), accy);
      zsv += p;
    }
  }
  accx += __shfl_xor(accx, 32, 64);
  accy += __shfl_xor(accy, 32, 64);
  zsv += __shfl_xor(zsv, 32, 64);
  {
    const float a = asrc[d * 8 + H] + ad_H;
    const float p = __expf(fmaxf(a, NEG * a));
    const uint u = *(const uint*)&h1g[d * 64 + 2 * cp];
    accx = fmaf(p, h2f((ushort)(u & 0xffff)), accx);
    accy = fmaf(p, h2f((ushort)(u >> 16)), accy);
    zsv += p;
  }
  const float inv = 1.0f / (zsv + 1e-16f);
  const float a0 = eluf(accx * inv + b1[2 * cp]);
  const float a1 = eluf(accy * inv + b1[2 * cp + 1]);
  acts[wave][2 * cp] = a0;
  acts[wave][2 * cp + 1] = a1;
  __syncthreads();

  float val = 0.0f;
  if (lane < 40) {
#pragma unroll
    for (int c = 0; c < 64; c += 4) {
      float4 a = *(const float4*)&acts[wave][c];
      val += a.x * w2s[(c + 0) * 40 + lane] + a.y * w2s[(c + 1) * 40 + lane] +
             a.z * w2s[(c + 2) * 40 + lane] + a.w * w2s[(c + 3) * 40 + lane];
    }
  }
  if (valid && lane < 40) h2g[(size_t)gw * 40 + lane] = f2h(val);

  float v1 = lane < 40 ? val * as2[lane] : 0.0f;
  float v2 = lane < 40 ? val * ad2[lane] : 0.0f;
#pragma unroll
  for (int o = 1; o < 64; o <<= 1) {
    v1 += __shfl_xor(v1, o, 64);
    v2 += __shfl_xor(v2, o, 64);
  }
  if (valid && lane == 0) {
    asrc2[gw] = v1;
    adst2[gw] = v2;
  }
}

// ---------------- layer 2 aggregation (paired-channel): wave per dst ----------------
__global__ __launch_bounds__(256) void agg2(const int* __restrict__ rowstart,
                                            const int* __restrict__ deg,
                                            const int* __restrict__ csr,
                                            const float* __restrict__ asrc,
                                            const float* __restrict__ adst,
                                            const ushort* __restrict__ h2g,
                                            const float* __restrict__ b2,
                                            float* __restrict__ out, int N) {
  int wid = (blockIdx.x * 256 + threadIdx.x) >> 6;
  if (wid >= N) return;
  const int lane = threadIdx.x & 63;
  const int cp = lane & 31;
  const int el = lane >> 5;
  const int cl = lane & 7;
  const int d = wid;
  const float ad = adst[d];
  const int rs = rowstart[d];
  const int n = deg[d];
  const int np = (n + 7) & ~7;
  float accx = 0.0f, accy = 0.0f, zsv = 0.0f;
  for (int i = 0; i < np; i += 8) {
    const int4 A = *(const int4*)&csr[rs + i];
    const int4 B = *(const int4*)&csr[rs + i + 4];
    const int sl = csr[rs + i + cl];
    const float al = asrc[sl] + ad;
    const float pl = __expf(fmaxf(al, NEG * al));
    int se[4], so[4];
    se[0] = A.x; so[0] = A.y; se[1] = A.z; so[1] = A.w;
    se[2] = B.x; so[2] = B.y; se[3] = B.z; so[3] = B.w;
#pragma unroll
    for (int j = 0; j < 4; ++j) {
      const int s = el ? so[j] : se[j];
      const float p = __shfl(pl, el + 2 * j, 64);
      const uint u = *(const uint*)&h2g[s * 40 + 2 * cp];
      accx = fmaf(p, h2f((ushort)(u & 0xffff)), accx);
      accy = fmaf(p, h2f((ushort)(u >> 16)), accy);
      zsv += p;
    }
  }
  accx += __shfl_xor(accx, 32, 64);
  accy += __shfl_xor(accy, 32, 64);
  zsv += __shfl_xor(zsv, 32, 64);
  {
    const float a = asrc[d] + ad;
    const float p = __expf(fmaxf(a, NEG * a));
    const uint u = *(const uint*)&h2g[d * 40 + 2 * cp];
    accx = fmaf(p, h2f((ushort)(u & 0xffff)), accx);
    accy = fmaf(p, h2f((ushort)(u >> 16)), accy);
    zsv += p;
  }
  if (cp < 20) {
    const float inv = 1.0f / (zsv + 1e-16f);
    out[(size_t)d * 40 + 2 * cp] = accx * inv + b2[2 * cp];
    out[(size_t)d * 40 + 2 * cp + 1] = accy * inv + b2[2 * cp + 1];
  }
}

extern "C" void kernel_launch(void* const* d_in, const int* in_sizes, int n_in,
                              void* d_out, int out_size, void* d_ws, size_t ws_size,
                              hipStream_t stream) {
  const float* x   = (const float*)d_in[0];
  const int*   ei  = (const int*)d_in[1];
  const float* W1  = (const float*)d_in[2];
  const float* as1 = (const float*)d_in[3];
  const float* ad1 = (const float*)d_in[4];
  const float* b1  = (const float*)d_in[5];
  const float* W2  = (const float*)d_in[6];
  const float* as2 = (const float*)d_in[7];
  const float* ad2 = (const float*)d_in[8];
  const float* b2  = (const float*)d_in[9];
  float* out = (float*)d_out;

  const int N = in_sizes[0] / 512;
  const int E = in_sizes[1] / 2;
  const int NBK = (N + CNODES - 1) / CNODES;

  float* ws = (float*)d_ws;
  size_t o = 0;
  float* asrc1 = ws + o; o += (size_t)N * 8 + 8;
  float* adst1 = ws + o; o += (size_t)N * 8;
  float* asrc2 = ws + o; o += (size_t)N + 1;
  float* adst2 = ws + o; o += (size_t)N;
  ushort* h1g  = (ushort*)(ws + o); o += (size_t)N * 32 + 64;
  ushort* h2g  = (ushort*)(ws + o); o += (size_t)N * 20 + 64;
  ushort* wt_h = (ushort*)(ws + o); o += 64 * 512 / 2 + 16;   // fp16 W^T [64][512]
  int* deg         = (int*)(ws + o); o += (size_t)N;
  int* rowstart    = (int*)(ws + o); o += (size_t)N;
  int* coarse_hist = (int*)(ws + o); o += 1024;
  int* coarse_off  = (int*)(ws + o); o += 1056;
  int* cursor      = (int*)(ws + o); o += 1024;
  int* bucketed    = (int*)(ws + o); o += (size_t)E;
  int* csr         = (int*)(ws + o); o += (size_t)E + 8 * CNODES * (size_t)NBK + 64;

  hipMemsetAsync(coarse_hist, 0, 1024 * sizeof(int), stream);
  hipMemsetAsync(h1g + (size_t)N * 64, 0, 128 * sizeof(ushort), stream);
  hipMemsetAsync(h2g + (size_t)N * 40, 0, 64 * sizeof(ushort), stream);

  const int NBg = (N + 63) / 64;
  const int NBc = (E + 16383) / 16384;
  const int NB3 = (E + 16383) / 16384;

  k_wt<<<8, 256, 0, stream>>>(W1, wt_h);
  k_hist<<<NBc, 256, 0, stream>>>(ei, coarse_hist, E, NBK);
  k_coarse_scan<<<1, 1024, 0, stream>>>(coarse_hist, coarse_off, cursor, asrc1, asrc2,
                                        NBK, E, N);

  k_gemm_scatter<<<NBg + NB3, 256, 0, stream>>>(x, wt_h, h1g, as1, ad1, asrc1, adst1, ei,
                                                cursor, bucketed, N, E, NBg, NBK);

  k_fine_csr<<<NBK, 256, 0, stream>>>(bucketed, coarse_off, rowstart, deg, csr, N);

  agg1_l2<<<(N * 64 + 255) / 256, 256, 0, stream>>>(rowstart, deg, csr, asrc1, adst1, h1g,
                                                    b1, W2, as2, ad2, h2g, asrc2, adst2, N);

  agg2<<<(N * 64 + 255) / 256, 256, 0, stream>>>(rowstart, deg, csr, asrc2, adst2, h2g, b2,
                                                 out, N);
}